// Round 8
// baseline (377.332 us; speedup 1.0000x reference)
//
#include <hip/hip_runtime.h>
#include <cstdint>
#include <cmath>

typedef unsigned short u16;
typedef __attribute__((ext_vector_type(8))) short short8;
typedef __attribute__((ext_vector_type(4))) float f32x4;

#define BB 4
#define NTOK 4096
#define CDIM 512
#define NROWS (BB * NTOK)
#define QSCALE 0.0441941738241592f  // 1/sqrt(512)

__device__ __forceinline__ u16 f2bf(float f) {
  union { float f; uint32_t u; } v; v.f = f;
  return (u16)((v.u + 0x7fffu + ((v.u >> 16) & 1u)) >> 16);
}

__device__ __forceinline__ float bf2f(u16 u) {
  union { uint32_t u; float f; } v; v.u = (uint32_t)u << 16;
  return v.f;
}

__device__ __forceinline__ f32x4 mfma16(short8 a, short8 b, f32x4 c) {
  return __builtin_amdgcn_mfma_f32_16x16x32_bf16(a, b, c, 0, 0, 0);
}

__device__ __forceinline__ void gload16(const u16* g, u16* l) {
  __builtin_amdgcn_global_load_lds(
      (const __attribute__((address_space(1))) void*)g,
      (__attribute__((address_space(3))) void*)l, 16, 0, 0);
}

// ---------------- LayerNorm (one wave per row of 512) ----------------
__global__ __launch_bounds__(256) void ln_kernel(const float* __restrict__ x,
                                                 const float* __restrict__ gam,
                                                 const float* __restrict__ bet,
                                                 u16* __restrict__ hn) {
  int row = blockIdx.x * 4 + (threadIdx.x >> 6);
  int lane = threadIdx.x & 63;
  const float4* xr = (const float4*)(x + (size_t)row * CDIM);
  float4 a0 = xr[lane];
  float4 a1 = xr[lane + 64];
  float s = a0.x + a0.y + a0.z + a0.w + a1.x + a1.y + a1.z + a1.w;
  float ss = a0.x * a0.x + a0.y * a0.y + a0.z * a0.z + a0.w * a0.w +
             a1.x * a1.x + a1.y * a1.y + a1.z * a1.z + a1.w * a1.w;
#pragma unroll
  for (int j = 0; j < 6; ++j) {
    s += __shfl_xor(s, 1 << j);
    ss += __shfl_xor(ss, 1 << j);
  }
  float mu = s * (1.0f / CDIM);
  float var = ss * (1.0f / CDIM) - mu * mu;
  float rs = rsqrtf(var + 1e-3f);
  const float4* g4 = (const float4*)gam;
  const float4* b4 = (const float4*)bet;
  float4 g0 = g4[lane], g1 = g4[lane + 64];
  float4 c0 = b4[lane], c1 = b4[lane + 64];
  u16* out = hn + (size_t)row * CDIM;
  ushort4 o0, o1;
  o0.x = f2bf((a0.x - mu) * rs * g0.x + c0.x);
  o0.y = f2bf((a0.y - mu) * rs * g0.y + c0.y);
  o0.z = f2bf((a0.z - mu) * rs * g0.z + c0.z);
  o0.w = f2bf((a0.w - mu) * rs * g0.w + c0.w);
  o1.x = f2bf((a1.x - mu) * rs * g1.x + c1.x);
  o1.y = f2bf((a1.y - mu) * rs * g1.y + c1.y);
  o1.z = f2bf((a1.z - mu) * rs * g1.z + c1.z);
  o1.w = f2bf((a1.w - mu) * rs * g1.w + c1.w);
  *(ushort4*)(out + lane * 4) = o0;
  *(ushort4*)(out + 256 + lane * 4) = o1;
}

// -- weights fp32 [K,N] -> bf16 W^T rows [Q|K|V|P] [2048,512]; Q pre-scaled.
__global__ __launch_bounds__(256) void wconv_kernel(
    const float* __restrict__ w0, const float* __restrict__ w1,
    const float* __restrict__ w2, const float* __restrict__ w3,
    const float* __restrict__ bq, const float* __restrict__ bk,
    const float* __restrict__ bv,
    u16* __restrict__ wt, float* __restrict__ bqkv) {
  __shared__ __align__(16) u16 tile[64][65];
  int which = blockIdx.z;
  const float* W = (which == 0) ? w0 : (which == 1) ? w1 : (which == 2) ? w2 : w3;
  float wscale = (which == 0) ? QSCALE : 1.0f;
  u16* WT = wt + (size_t)which * CDIM * CDIM;
  int kb = blockIdx.x * 64, nb = blockIdx.y * 64;
  int t = threadIdx.x;
  if (kb == 0 && which < 3 && t < 64) {
    const float* bs = (which == 0) ? bq : (which == 1) ? bk : bv;
    bqkv[which * CDIM + nb + t] = bs[nb + t] * wscale;
  }
#pragma unroll
  for (int i = 0; i < 16; ++i) {
    int idx = t + i * 256;
    int r = idx >> 6, c = idx & 63;
    tile[r][c] = f2bf(W[(size_t)(kb + r) * CDIM + nb + c] * wscale);
  }
  __syncthreads();
#pragma unroll
  for (int i = 0; i < 16; ++i) {
    int idx = t + i * 256;
    int r = idx >> 6, c = idx & 63;
    WT[(size_t)(nb + r) * CDIM + kb + c] = tile[c][r];
  }
}

// ------- bf16 src [BN, ld] (col window 64) -> vt [B, C, N] transpose -------
__global__ __launch_bounds__(256) void vtrans_kernel(const u16* __restrict__ v,
                                                     int ld,
                                                     u16* __restrict__ vt) {
  __shared__ __align__(16) u16 tile[64][65];
  int nb = blockIdx.x * 64;
  int cb = blockIdx.y * 64;
  int b = blockIdx.z;
  int t = threadIdx.x;
  const u16* src = v + ((size_t)b * NTOK + nb) * ld + cb;
#pragma unroll
  for (int i = 0; i < 16; ++i) {
    int idx = t + i * 256;
    int r = idx >> 6, c = idx & 63;
    tile[r][c] = src[(size_t)r * ld + c];
  }
  __syncthreads();
  u16* dst = vt + ((size_t)b * CDIM + cb) * NTOK + nb;
#pragma unroll
  for (int i = 0; i < 16; ++i) {
    int idx = t + i * 256;
    int r = idx >> 6, c = idx & 63;
    dst[(size_t)r * NTOK + c] = tile[c][r];
  }
}

// ====== 256x256 GEMM, 8 waves (2M x 4N), BK=64, 8-phase schedule ======
// m201-style: per iteration (2 K-tiles of 64), 8 phases of
// {ds-reads for this phase's quadrant | stage 1 half-tile (2 gload_lds)
//  | [vmcnt(2) at P4/P8] | barrier | lgkmcnt(0) | setprio(1) 16 MFMA setprio(0)}
// LDS [dbuf][A|B][half 128 rows][64] = 128 KB. Swizzle: 16B slot ^= row&7
// (conflict-free column reads); linear gload dest + pre-swizzled source.
// Region-lifetime verified: every stage >= last-read + 2 phases; vmcnt(2)
// at P4/P8 certifies the 4 regions consumed in the following 3 phases.
// MODE 0: bf16 acc+bias | MODE 2: bf16 acc | MODE 3: bf16 acc/lsum[row]
template <int MODE, int LOGSPLIT>
__global__ __launch_bounds__(512) void gemm256_kernel(
    const u16* __restrict__ A, int lda, size_t az,
    const u16* __restrict__ Bt, int ldb, size_t bz,
    const float* __restrict__ bias,
    const float* __restrict__ lsum, int lz,
    u16* __restrict__ outp, int ldo, size_t oz, size_t koz,
    int K) {
  // [dbuf][ab][half] regions of 8192 u16 (128 rows x 64)
  __shared__ __align__(16) u16 lds[8][8192];
  int t = threadIdx.x;
  int w = t >> 6, lane = t & 63;
  int lr = lane & 15, lg = lane >> 4;
  int wr = w >> 2, wc = w & 3;
  // --- XCD-chunked bijective swizzle (nwg % 8 == 0 at all call sites) ---
  int gx = gridDim.x, gy = gridDim.y;
  int nwg = gx * gy * (int)gridDim.z;
  int n = blockIdx.x + gx * (blockIdx.y + gy * blockIdx.z);
  int cpx = nwg >> 3;
  int swz = (n & 7) * cpx + (n >> 3);
  int bx = swz % gx;
  int rem = swz / gx;
  int by = rem % gy;
  int bz2 = rem / gy;
  int batch = bz2 >> LOGSPLIT;
  int kq = bz2 & ((1 << LOGSPLIT) - 1);
  size_t aoff = az * (size_t)batch + (size_t)kq * K;
  size_t boff = bz * (size_t)batch + (size_t)kq * K;
  size_t ooff = oz * (size_t)batch + koz * (size_t)kq;
  int lsrow0 = lz * batch;
  int mbase = by * 256, nbase = bx * 256;
  const f32x4 fz = {0.f, 0.f, 0.f, 0.f};
  f32x4 acc[8][4];
#pragma unroll
  for (int m = 0; m < 8; ++m)
#pragma unroll
    for (int n2 = 0; n2 < 4; ++n2) acc[m][n2] = fz;

  // staging geometry: thread t covers row srow(+64), phys slot t&7 (16B).
  // phys slot p of row r holds logical slot p ^ (r&7): source pre-swizzled.
  int srow = t >> 3;
  int scol = ((t & 7) ^ (srow & 7)) * 8;
  const u16* ga = A + aoff + (size_t)(mbase + srow) * lda + scol;
  const u16* gb = Bt + boff + (size_t)(nbase + srow) * ldb + scol;

  // read-side: logical slot ks*4+lg at row -> phys (ks*4+lg)^(lr&7)
  int ps0 = (lg ^ (lr & 7)) * 8;  // ks=0 slot byte-offset/2 (u16 elems)

  // stage region (ab,h) of K-tile `tile` into dbuf d: 2 gload16
#define STG_A(h, tile, d)                                                   \
  {                                                                         \
    const u16* s_ = ga + (size_t)((h)*128) * lda + (tile)*64;               \
    u16* d_ = &lds[(d)*4 + (h)][0] + w * 512;                               \
    gload16(s_, d_);                                                        \
    gload16(s_ + (size_t)64 * lda, d_ + 4096);                              \
  }
#define STG_B(h, tile, d)                                                   \
  {                                                                         \
    const u16* s_ = gb + (size_t)((h)*128) * ldb + (tile)*64;               \
    u16* d_ = &lds[(d)*4 + 2 + (h)][0] + w * 512;                           \
    gload16(s_, d_);                                                        \
    gload16(s_ + (size_t)64 * ldb, d_ + 4096);                              \
  }

  // reads: A-set (8 b128) for m-half mh; B-set (4 b128) for n-half nh
#define RD_A(dst, d, mh)                                                    \
  {                                                                         \
    const u16* b_ = &lds[(d)*4 + wr][0] + ((mh)*64 + lr) * 64 + ps0;        \
    _Pragma("unroll") for (int m = 0; m < 4; ++m) {                         \
      dst[m * 2 + 0] = *(const short8*)(b_ + m * 1024);                     \
      dst[m * 2 + 1] = *(const short8*)((const u16*)((size_t)(b_ + m * 1024)) + \
                                        (((ps0 >> 3) ^ 4) * 8 - ps0));      \
    }                                                                       \
  }
#define RD_B(dst, d, nh)                                                    \
  {                                                                         \
    const u16* b_ = &lds[(d)*4 + 2 + (wc >> 1)][0] +                        \
                    ((wc & 1) * 64 + (nh)*32 + lr) * 64 + ps0;              \
    _Pragma("unroll") for (int n2 = 0; n2 < 2; ++n2) {                      \
      dst[n2 * 2 + 0] = *(const short8*)(b_ + n2 * 1024);                   \
      dst[n2 * 2 + 1] = *(const short8*)((const u16*)((size_t)(b_ + n2 * 1024)) + \
                                         (((ps0 >> 3) ^ 4) * 8 - ps0));     \
    }                                                                       \
  }

#define PHEND                                                               \
  asm volatile("" ::: "memory");                                            \
  __builtin_amdgcn_sched_barrier(0);                                        \
  __builtin_amdgcn_s_barrier();                                             \
  asm volatile("s_waitcnt lgkmcnt(0)" ::: "memory");                        \
  __builtin_amdgcn_sched_barrier(0);

#define VM2 asm volatile("s_waitcnt vmcnt(2)" ::: "memory");
#define VM0 asm volatile("s_waitcnt vmcnt(0)" ::: "memory");

  // 16 MFMA on quadrant (mq, nq)
#define MM(X, Y, mq, nq)                                                    \
  __builtin_amdgcn_s_setprio(1);                                            \
  _Pragma("unroll") for (int m = 0; m < 4; ++m)                             \
      _Pragma("unroll") for (int n2 = 0; n2 < 2; ++n2)                      \
          _Pragma("unroll") for (int ks = 0; ks < 2; ++ks)                  \
              acc[(mq)*4 + m][(nq)*2 + n2] =                                \
                  mfma16(X[m * 2 + ks], Y[n2 * 2 + ks],                     \
                         acc[(mq)*4 + m][(nq)*2 + n2]);                     \
  __builtin_amdgcn_s_setprio(0);

  short8 A0f[8], A1f[8], B0f[4], B1f[4];
  int niter = K >> 7;  // K/128, >= 4 at all call sites

  // prologue: T0 full -> dbuf0, T1.Ah0 -> dbuf1; certify T0 (leave T1.Ah0)
  STG_A(0, 0, 0); STG_B(0, 0, 0); STG_A(1, 0, 0); STG_B(1, 0, 0);
  STG_A(0, 1, 1);
  VM2;
  __builtin_amdgcn_s_barrier();
  asm volatile("" ::: "memory");

  for (int j = 0; j < niter; ++j) {
    int T1i = 2 * j + 1, T2i = 2 * j + 2, T3i = 2 * j + 3;
    bool more = (j + 1 < niter);
    // P1: rd A0,B0 (d0); stage Ah1(T1i->d1)
    RD_A(A0f, 0, 0); RD_B(B0f, 0, 0);
    STG_A(1, T1i, 1);
    PHEND; MM(A0f, B0f, 0, 0);
    // P2: rd A1 (d0); stage Bh0(T1i->d1)
    RD_A(A1f, 0, 1);
    STG_B(0, T1i, 1);
    PHEND; MM(A1f, B0f, 1, 0);
    // P3: rd B1 (d0); stage Bh1(T1i->d1)
    RD_B(B1f, 0, 1);
    STG_B(1, T1i, 1);
    PHEND; MM(A1f, B1f, 1, 1);
    // P4: stage Ah0(T2i->d0); vmcnt certifies T1i's 4 regions
    if (more) { STG_A(0, T2i, 0); VM2; } else { VM0; }
    PHEND; MM(A0f, B1f, 0, 1);
    // P5: rd A0,B0 (d1); stage Bh0(T2i->d0)
    RD_A(A0f, 1, 0); RD_B(B0f, 1, 0);
    if (more) STG_B(0, T2i, 0);
    PHEND; MM(A0f, B0f, 0, 0);
    // P6: rd A1 (d1); stage Ah1(T2i->d0)
    RD_A(A1f, 1, 1);
    if (more) STG_A(1, T2i, 0);
    PHEND; MM(A1f, B0f, 1, 0);
    // P7: rd B1 (d1); stage Bh1(T2i->d0)
    RD_B(B1f, 1, 1);
    if (more) STG_B(1, T2i, 0);
    PHEND; MM(A1f, B1f, 1, 1);
    // P8: stage Ah0(T3i->d1); vmcnt certifies T2i's 4 regions
    if (more) { STG_A(0, T3i, 1); VM2; } else { VM0; }
    PHEND; MM(A0f, B1f, 0, 1);
  }
#undef MM
#undef VM2
#undef VM0
#undef PHEND
#undef RD_A
#undef RD_B
#undef STG_A
#undef STG_B

  u16* op = outp + ooff;
#pragma unroll
  for (int m = 0; m < 8; ++m) {
    int grow = mbase + wr * 128 + m * 16 + lg * 4;
    float rl[4];
    if (MODE == 3) {
#pragma unroll
      for (int r = 0; r < 4; ++r)
        rl[r] = 1.0f / lsum[lsrow0 + grow + r];
    }
#pragma unroll
    for (int n2 = 0; n2 < 4; ++n2) {
      int gcol = nbase + wc * 64 + n2 * 16 + lr;
      float bnc = (MODE == 0) ? bias[gcol] : 0.f;
#pragma unroll
      for (int r = 0; r < 4; ++r) {
        size_t idx = (size_t)(grow + r) * ldo + gcol;
        float val = acc[m][n2][r];
        if (MODE == 0) {
          op[idx] = f2bf(val + bnc);
        } else if (MODE == 2) {
          op[idx] = f2bf(val);
        } else {
          op[idx] = f2bf(val * rl[r]);
        }
      }
    }
  }
}

// ====== 128x128 GEMM (final projection): f32 store acc+bias+res ======
__global__ __launch_bounds__(256) void gemm_fin_kernel(
    const u16* __restrict__ A, int lda,
    const u16* __restrict__ Bt, int ldb,
    const float* __restrict__ bias, const float* __restrict__ res,
    float* __restrict__ outp, int ldo, int K) {
  __shared__ __align__(16) u16 Als[2][128 * 32];
  __shared__ __align__(16) u16 Bls[2][128 * 32];
  int t = threadIdx.x;
  int w = t >> 6, lane = t & 63;
  int lr = lane & 15, lg = lane >> 4;
  int wr = w >> 1, wc = w & 1;
  int mbase = blockIdx.y * 128, nbase = blockIdx.x * 128;
  const f32x4 fz = {0.f, 0.f, 0.f, 0.f};
  f32x4 acc[4][4];
#pragma unroll
  for (int m = 0; m < 4; ++m)
#pragma unroll
    for (int n = 0; n < 4; ++n) acc[m][n] = fz;

  int scol = (((t & 3) ^ ((t >> 2) & 3) ^ ((t >> 4) & 1)) * 8);
  const u16* ga0 = A + (size_t)(mbase + (t >> 2)) * lda + scol;
  const u16* gb0 = Bt + (size_t)(nbase + (t >> 2)) * ldb + scol;
  int rsA = (lg ^ (lr & 3) ^ ((lr >> 2) & 1)) * 8;

#define STAGE(buf, ko)                                                 \
  {                                                                    \
    gload16(ga0 + (ko), &Als[buf][w * 512]);                           \
    gload16(ga0 + (size_t)64 * lda + (ko), &Als[buf][w * 512 + 2048]); \
    gload16(gb0 + (ko), &Bls[buf][w * 512]);                           \
    gload16(gb0 + (size_t)64 * ldb + (ko), &Bls[buf][w * 512 + 2048]); \
  }

  int nk = K >> 5;
  STAGE(0, 0);
  STAGE(1, 32);
  int cur = 0;
  for (int kt = 0; kt < nk; ++kt) {
    if (kt + 1 < nk) {
      asm volatile("s_waitcnt vmcnt(4)" ::: "memory");
    } else {
      asm volatile("s_waitcnt vmcnt(0)" ::: "memory");
    }
    __builtin_amdgcn_s_barrier();
    asm volatile("" ::: "memory");
    __builtin_amdgcn_sched_barrier(0);
    short8 af[4], bfr[4];
#pragma unroll
    for (int m = 0; m < 4; ++m)
      af[m] = *(const short8*)(&Als[cur][(wr * 64 + m * 16 + lr) * 32 + rsA]);
#pragma unroll
    for (int n = 0; n < 4; ++n)
      bfr[n] = *(const short8*)(&Bls[cur][(wc * 64 + n * 16 + lr) * 32 + rsA]);
#pragma unroll
    for (int m = 0; m < 4; ++m)
#pragma unroll
      for (int n = 0; n < 4; ++n)
        acc[m][n] = mfma16(af[m], bfr[n], acc[m][n]);
    asm volatile("s_waitcnt lgkmcnt(0)" ::: "memory");
    __builtin_amdgcn_s_barrier();
    asm volatile("" ::: "memory");
    if (kt + 2 < nk) STAGE(cur, (kt + 2) * 32);
    cur ^= 1;
  }
#undef STAGE

#pragma unroll
  for (int m = 0; m < 4; ++m) {
    int grow = mbase + wr * 64 + m * 16 + lg * 4;
#pragma unroll
    for (int n = 0; n < 4; ++n) {
      int gcol = nbase + wc * 64 + n * 16 + lr;
      float bnc = bias[gcol];
#pragma unroll
      for (int r = 0; r < 4; ++r) {
        size_t idx = (size_t)(grow + r) * ldo + gcol;
        outp[idx] = acc[m][n][r] + bnc + res[idx];
      }
    }
  }
}

// ---- softmax over rows of 4096 bf16, in-place, one wave per row ----
__global__ __launch_bounds__(256) void softmax_kernel(u16* __restrict__ S,
                                                      float* __restrict__ lsum) {
  int row = blockIdx.x * 4 + (threadIdx.x >> 6);
  int lane = threadIdx.x & 63;
  u16* Sr = S + (size_t)row * NTOK;
  short8 d[8];
#pragma unroll
  for (int i = 0; i < 8; ++i)
    d[i] = *(const short8*)(Sr + i * 512 + lane * 8);
  float mx = -1e30f;
#pragma unroll
  for (int i = 0; i < 8; ++i)
#pragma unroll
    for (int j = 0; j < 8; ++j) mx = fmaxf(mx, bf2f((u16)d[i][j]));
#pragma unroll
  for (int j = 0; j < 6; ++j) mx = fmaxf(mx, __shfl_xor(mx, 1 << j));
  float sum = 0.f;
#pragma unroll
  for (int i = 0; i < 8; ++i) {
    short8 o;
#pragma unroll
    for (int j = 0; j < 8; ++j) {
      float p = __expf(bf2f((u16)d[i][j]) - mx);
      sum += p;
      o[j] = (short)f2bf(p);
    }
    *(short8*)(Sr + i * 512 + lane * 8) = o;
  }
#pragma unroll
  for (int j = 0; j < 6; ++j) sum += __shfl_xor(sum, 1 << j);
  if (lane == 0) lsum[row] = sum;
}

// ---- sum four bf16 partial slices (stride ss) -> bf16 ----
__global__ __launch_bounds__(256) void addp4_kernel(const u16* __restrict__ p,
                                                    size_t ss,
                                                    u16* __restrict__ ob) {
  size_t i = ((size_t)blockIdx.x * 256 + threadIdx.x) * 8;
  short8 a0 = *(const short8*)(p + i);
  short8 a1 = *(const short8*)(p + ss + i);
  short8 a2 = *(const short8*)(p + 2 * ss + i);
  short8 a3 = *(const short8*)(p + 3 * ss + i);
  short8 o;
#pragma unroll
  for (int j = 0; j < 8; ++j)
    o[j] = (short)f2bf(bf2f((u16)a0[j]) + bf2f((u16)a1[j]) +
                       bf2f((u16)a2[j]) + bf2f((u16)a3[j]));
  *(short8*)(ob + i) = o;
}

extern "C" void kernel_launch(void* const* d_in, const int* in_sizes, int n_in,
                              void* d_out, int out_size, void* d_ws, size_t ws_size,
                              hipStream_t stream) {
  (void)in_sizes; (void)n_in; (void)out_size;
  const float* x    = (const float*)d_in[0];
  const float* ln_g = (const float*)d_in[1];
  const float* ln_b = (const float*)d_in[2];
  const float* Wq   = (const float*)d_in[3];
  const float* bq   = (const float*)d_in[4];
  const float* Wk   = (const float*)d_in[5];
  const float* bk   = (const float*)d_in[6];
  const float* Wv   = (const float*)d_in[7];
  const float* bv   = (const float*)d_in[8];
  const float* Wp   = (const float*)d_in[9];
  const float* bp   = (const float*)d_in[10];

  const size_t MB = 1024ull * 1024ull;
  const size_t KB = 1024ull;
  char* ws = (char*)d_ws;
  u16* wt     = (u16*)(ws);                       // 2 MB [Q|K|V|P] W^T bf16
  float* bqkv = (float*)(ws + 2 * MB);            // 6 KB concat scaled bias
  float* ls   = (float*)(ws + 2 * MB + 64 * KB);  // 64 KB row sums
  u16* hn     = (u16*)(ws + 4 * MB);              // 16 MB (dead after proj)
  u16* qkv    = (u16*)(ws + 20 * MB);             // 48 MB [16384,1536]
  u16* vt     = (u16*)(ws + 68 * MB);             // 16 MB
  bool full = ws_size >= 212 * MB;
  u16* S    = (u16*)(ws + 84 * MB);   // 128 MB (full) / 32 MB (fallback)
  // PV split-K=4 partials: 4 x 16 MB = 64 MB over dead hn+qkv (full path)
  u16* part = (u16*)(ws + 4 * MB);
  u16* ob   = full ? vt : (u16*)(ws + 116 * MB);  // vt dead after PV (full)

  const float* nullf = nullptr;

  hipLaunchKernelGGL(wconv_kernel, dim3(8, 8, 4), dim3(256), 0, stream,
                     Wq, Wk, Wv, Wp, bq, bk, bv, wt, bqkv);
  hipLaunchKernelGGL(ln_kernel, dim3(NROWS / 4), dim3(256), 0, stream,
                     x, ln_g, ln_b, hn);
  // fused QKV projection: [16384,512] x [1536,512]^T -> qkv [16384,1536]
  hipLaunchKernelGGL((gemm256_kernel<0, 0>), dim3(6, 64, 1), dim3(512), 0,
                     stream, hn, CDIM, (size_t)0, wt, CDIM, (size_t)0,
                     bqkv, nullf, 0, qkv, 3 * CDIM, (size_t)0, (size_t)0, CDIM);
  // V columns of qkv -> vt [B, C, N]
  hipLaunchKernelGGL(vtrans_kernel, dim3(64, 8, 4), dim3(256), 0, stream,
                     qkv + 2 * CDIM, 3 * CDIM, vt);

  if (full) {
    // S = Q K^T : M=N=4096, K=512, z=4 batches
    hipLaunchKernelGGL((gemm256_kernel<2, 0>), dim3(16, 16, 4), dim3(512), 0,
                       stream, qkv, 3 * CDIM, (size_t)NTOK * 3 * CDIM,
                       qkv + CDIM, 3 * CDIM, (size_t)NTOK * 3 * CDIM,
                       nullf, nullf, 0,
                       S, NTOK, (size_t)NTOK * NTOK, (size_t)0, CDIM);
    hipLaunchKernelGGL(softmax_kernel, dim3(4 * NTOK / 4), dim3(256), 0, stream,
                       S, ls);
    // O = P V, split-K=4: z = batch*4+kq; partials into part[kq][batch]
    hipLaunchKernelGGL((gemm256_kernel<3, 2>), dim3(2, 16, 16), dim3(512), 0,
                       stream, S, NTOK, (size_t)NTOK * NTOK,
                       vt, NTOK, (size_t)CDIM * NTOK,
                       nullf, ls, NTOK,
                       part, CDIM, (size_t)NTOK * CDIM,
                       (size_t)NROWS * CDIM, NTOK / 4);
    hipLaunchKernelGGL(addp4_kernel, dim3(NROWS * CDIM / 2048), dim3(256), 0,
                       stream, part, (size_t)NROWS * CDIM, ob);
  } else {
    for (int p = 0; p < 4; ++p) {
      const u16* qp  = qkv + (size_t)p * NTOK * 3 * CDIM;
      const u16* kp  = qp + CDIM;
      const u16* vtp = vt + (size_t)p * CDIM * NTOK;
      u16* obp = ob + (size_t)p * NTOK * CDIM;
      float* lp = ls + (size_t)p * NTOK;
      hipLaunchKernelGGL((gemm256_kernel<2, 0>), dim3(16, 16, 1), dim3(512), 0,
                         stream, qp, 3 * CDIM, (size_t)0, kp, 3 * CDIM,
                         (size_t)0, nullf, nullf, 0,
                         S, NTOK, (size_t)0, (size_t)0, CDIM);
      hipLaunchKernelGGL(softmax_kernel, dim3(NTOK / 4), dim3(256), 0, stream,
                         S, lp);
      hipLaunchKernelGGL((gemm256_kernel<3, 0>), dim3(2, 16, 1), dim3(512), 0,
                         stream, S, NTOK, (size_t)0, vtp, NTOK, (size_t)0,
                         nullf, lp, 0,
                         obp, CDIM, (size_t)0, (size_t)0, NTOK);
    }
  }
  // final: out = O Wp + bp + x  (f32)
  hipLaunchKernelGGL(gemm_fin_kernel, dim3(4, 128), dim3(256), 0, stream,
                     ob, CDIM, wt + 3 * CDIM * CDIM, CDIM,
                     bp, x, (float*)d_out, CDIM, CDIM);
}

// Round 9
// 316.238 us; speedup vs baseline: 1.1932x; 1.1932x over previous
//
#include <hip/hip_runtime.h>
#include <cstdint>
#include <cmath>

typedef unsigned short u16;
typedef __attribute__((ext_vector_type(8))) short short8;
typedef __attribute__((ext_vector_type(4))) float f32x4;

#define BB 4
#define NTOK 4096
#define CDIM 512
#define NROWS (BB * NTOK)
#define QSCALE 0.0441941738241592f  // 1/sqrt(512)

__device__ __forceinline__ u16 f2bf(float f) {
  union { float f; uint32_t u; } v; v.f = f;
  return (u16)((v.u + 0x7fffu + ((v.u >> 16) & 1u)) >> 16);
}

__device__ __forceinline__ float bf2f(u16 u) {
  union { uint32_t u; float f; } v; v.u = (uint32_t)u << 16;
  return v.f;
}

__device__ __forceinline__ f32x4 mfma16(short8 a, short8 b, f32x4 c) {
  return __builtin_amdgcn_mfma_f32_16x16x32_bf16(a, b, c, 0, 0, 0);
}

__device__ __forceinline__ void gload16(const u16* g, u16* l) {
  __builtin_amdgcn_global_load_lds(
      (const __attribute__((address_space(1))) void*)g,
      (__attribute__((address_space(3))) void*)l, 16, 0, 0);
}

// ---------------- LayerNorm (one wave per row of 512) ----------------
__global__ __launch_bounds__(256) void ln_kernel(const float* __restrict__ x,
                                                 const float* __restrict__ gam,
                                                 const float* __restrict__ bet,
                                                 u16* __restrict__ hn) {
  int row = blockIdx.x * 4 + (threadIdx.x >> 6);
  int lane = threadIdx.x & 63;
  const float4* xr = (const float4*)(x + (size_t)row * CDIM);
  float4 a0 = xr[lane];
  float4 a1 = xr[lane + 64];
  float s = a0.x + a0.y + a0.z + a0.w + a1.x + a1.y + a1.z + a1.w;
  float ss = a0.x * a0.x + a0.y * a0.y + a0.z * a0.z + a0.w * a0.w +
             a1.x * a1.x + a1.y * a1.y + a1.z * a1.z + a1.w * a1.w;
#pragma unroll
  for (int j = 0; j < 6; ++j) {
    s += __shfl_xor(s, 1 << j);
    ss += __shfl_xor(ss, 1 << j);
  }
  float mu = s * (1.0f / CDIM);
  float var = ss * (1.0f / CDIM) - mu * mu;
  float rs = rsqrtf(var + 1e-3f);
  const float4* g4 = (const float4*)gam;
  const float4* b4 = (const float4*)bet;
  float4 g0 = g4[lane], g1 = g4[lane + 64];
  float4 c0 = b4[lane], c1 = b4[lane + 64];
  u16* out = hn + (size_t)row * CDIM;
  ushort4 o0, o1;
  o0.x = f2bf((a0.x - mu) * rs * g0.x + c0.x);
  o0.y = f2bf((a0.y - mu) * rs * g0.y + c0.y);
  o0.z = f2bf((a0.z - mu) * rs * g0.z + c0.z);
  o0.w = f2bf((a0.w - mu) * rs * g0.w + c0.w);
  o1.x = f2bf((a1.x - mu) * rs * g1.x + c1.x);
  o1.y = f2bf((a1.y - mu) * rs * g1.y + c1.y);
  o1.z = f2bf((a1.z - mu) * rs * g1.z + c1.z);
  o1.w = f2bf((a1.w - mu) * rs * g1.w + c1.w);
  *(ushort4*)(out + lane * 4) = o0;
  *(ushort4*)(out + 256 + lane * 4) = o1;
}

// -- weights fp32 [K,N] -> bf16 W^T rows [Q|K|V|P] [2048,512]; Q pre-scaled.
__global__ __launch_bounds__(256) void wconv_kernel(
    const float* __restrict__ w0, const float* __restrict__ w1,
    const float* __restrict__ w2, const float* __restrict__ w3,
    const float* __restrict__ bq, const float* __restrict__ bk,
    const float* __restrict__ bv,
    u16* __restrict__ wt, float* __restrict__ bqkv) {
  __shared__ __align__(16) u16 tile[64][65];
  int which = blockIdx.z;
  const float* W = (which == 0) ? w0 : (which == 1) ? w1 : (which == 2) ? w2 : w3;
  float wscale = (which == 0) ? QSCALE : 1.0f;
  u16* WT = wt + (size_t)which * CDIM * CDIM;
  int kb = blockIdx.x * 64, nb = blockIdx.y * 64;
  int t = threadIdx.x;
  if (kb == 0 && which < 3 && t < 64) {
    const float* bs = (which == 0) ? bq : (which == 1) ? bk : bv;
    bqkv[which * CDIM + nb + t] = bs[nb + t] * wscale;
  }
#pragma unroll
  for (int i = 0; i < 16; ++i) {
    int idx = t + i * 256;
    int r = idx >> 6, c = idx & 63;
    tile[r][c] = f2bf(W[(size_t)(kb + r) * CDIM + nb + c] * wscale);
  }
  __syncthreads();
#pragma unroll
  for (int i = 0; i < 16; ++i) {
    int idx = t + i * 256;
    int r = idx >> 6, c = idx & 63;
    WT[(size_t)(nb + r) * CDIM + kb + c] = tile[c][r];
  }
}

// ------- bf16 src [BN, ld] (col window 64) -> vt [B, C, N] transpose -------
__global__ __launch_bounds__(256) void vtrans_kernel(const u16* __restrict__ v,
                                                     int ld,
                                                     u16* __restrict__ vt) {
  __shared__ __align__(16) u16 tile[64][65];
  int nb = blockIdx.x * 64;
  int cb = blockIdx.y * 64;
  int b = blockIdx.z;
  int t = threadIdx.x;
  const u16* src = v + ((size_t)b * NTOK + nb) * ld + cb;
#pragma unroll
  for (int i = 0; i < 16; ++i) {
    int idx = t + i * 256;
    int r = idx >> 6, c = idx & 63;
    tile[r][c] = src[(size_t)r * ld + c];
  }
  __syncthreads();
  u16* dst = vt + ((size_t)b * CDIM + cb) * NTOK + nb;
#pragma unroll
  for (int i = 0; i < 16; ++i) {
    int idx = t + i * 256;
    int r = idx >> 6, c = idx & 63;
    dst[(size_t)r * NTOK + c] = tile[c][r];
  }
}

// ====== 128x128 GEMM, 4 waves (2Mx2N), BK=32, reg-dbuf + depth-3 LDS ======
// R6-validated skeleton at 128^2: ONE barrier per K-step; step kt:
//   lgkm(0) (frags for this step landed) -> vmcnt(4)/(0) certify tile kt+1
//   -> barrier -> ds_reads tile kt+1 into alt reg set -> stage tile kt+3
//   into buf kt%3 (read last step, retired by lgkm+barrier) -> 16 MFMA.
// 48 KB LDS + ~<=180 regs -> 2-3 blocks/CU; independent blocks hide stalls.
// MODE 0: bf16 acc+bias, packed 3-way output (QKV proj, col>>9 selects q/k/v)
// MODE 1: f32 acc+bias+res (final)  MODE 2: bf16 acc (QK^T)
// MODE 3: bf16 acc/lsum[row] (PV)
// LOGSPLIT: z = batch<<LOGSPLIT | kq; kq offsets A/B cols by kq*K, out by koz.
template <int MODE, int LOGSPLIT>
__global__ __launch_bounds__(256) void g128_kernel(
    const u16* __restrict__ A, int lda, size_t az,
    const u16* __restrict__ Bt, int ldb, size_t bz,
    const float* __restrict__ bias, const float* __restrict__ res,
    const float* __restrict__ lsum, int lz,
    void* __restrict__ outp, int ldo, size_t oz, size_t koz,
    int K) {
  __shared__ __align__(16) u16 Als[3][4096];
  __shared__ __align__(16) u16 Bls[3][4096];
  int t = threadIdx.x;
  int w = t >> 6, lane = t & 63;
  int lr = lane & 15, lg = lane >> 4;
  int wr = w >> 1, wc = w & 1;
  // --- XCD-chunked bijective swizzle (nwg % 8 == 0 at all call sites) ---
  int gx = gridDim.x, gy = gridDim.y;
  int nwg = gx * gy * (int)gridDim.z;
  int nlin = blockIdx.x + gx * (blockIdx.y + gy * blockIdx.z);
  int cpx = nwg >> 3;
  int swz = (nlin & 7) * cpx + (nlin >> 3);
  int bx = swz % gx;
  int rem = swz / gx;
  int by = rem % gy;
  int bz2 = rem / gy;
  int batch = bz2 >> LOGSPLIT;
  int kq = bz2 & ((1 << LOGSPLIT) - 1);
  size_t aoff = az * (size_t)batch + (size_t)kq * K;
  size_t boff = bz * (size_t)batch + (size_t)kq * K;
  size_t ooff = oz * (size_t)batch + koz * (size_t)kq;
  int lsrow0 = lz * batch;
  int mbase = by * 128, nbase = bx * 128;
  const f32x4 fz = {0.f, 0.f, 0.f, 0.f};
  f32x4 acc[4][4];
#pragma unroll
  for (int m = 0; m < 4; ++m)
#pragma unroll
    for (int n = 0; n < 4; ++n) acc[m][n] = fz;

  // staging: thread t -> LDS row t>>2 (linear dest); global source col-slot
  // pre-swizzled; read slot rsA matches (rule #21 involution).
  int scol = (((t & 3) ^ ((t >> 2) & 3) ^ ((t >> 4) & 1)) * 8);
  const u16* ga0 = A + aoff + (size_t)(mbase + (t >> 2)) * lda + scol;
  const u16* gb0 = Bt + boff + (size_t)(nbase + (t >> 2)) * ldb + scol;
  int rsA = (lg ^ (lr & 3) ^ ((lr >> 2) & 1)) * 8;
  const u16* rab = &Als[0][0] + (wr * 64 + lr) * 32 + rsA;  // +m*512, +buf*4096
  const u16* rbb = &Bls[0][0] + (wc * 64 + lr) * 32 + rsA;

#define STAGE(buf, ko)                                                 \
  {                                                                    \
    u16* la_ = &Als[0][0] + (buf)*4096 + w * 512;                      \
    u16* lb_ = &Bls[0][0] + (buf)*4096 + w * 512;                      \
    gload16(ga0 + (ko), la_);                                          \
    gload16(ga0 + (size_t)64 * lda + (ko), la_ + 2048);                \
    gload16(gb0 + (ko), lb_);                                          \
    gload16(gb0 + (size_t)64 * ldb + (ko), lb_ + 2048);                \
  }

#define READS(buf, A_, B_)                                             \
  {                                                                    \
    const u16* ab_ = rab + (buf)*4096;                                 \
    const u16* bb_ = rbb + (buf)*4096;                                 \
    _Pragma("unroll") for (int m = 0; m < 4; ++m)                      \
        A_[m] = *(const short8*)(ab_ + m * 512);                       \
    _Pragma("unroll") for (int n = 0; n < 4; ++n)                      \
        B_[n] = *(const short8*)(bb_ + n * 512);                       \
  }

#define STEP(kt, CA, CB, NA, NB)                                       \
  {                                                                    \
    asm volatile("s_waitcnt lgkmcnt(0)" ::: "memory");                 \
    __builtin_amdgcn_sched_barrier(0);                                 \
    if ((kt) + 2 < nk) {                                               \
      asm volatile("s_waitcnt vmcnt(4)" ::: "memory");                 \
    } else {                                                           \
      asm volatile("s_waitcnt vmcnt(0)" ::: "memory");                 \
    }                                                                  \
    __builtin_amdgcn_s_barrier();                                      \
    asm volatile("" ::: "memory");                                     \
    __builtin_amdgcn_sched_barrier(0);                                 \
    if ((kt) + 1 < nk) READS(bR, NA, NB);                              \
    if ((kt) + 3 < nk) {                                               \
      int bS_ = bR + 2; if (bS_ >= 3) bS_ -= 3;                        \
      STAGE(bS_, ((kt) + 3) * 32);                                     \
    }                                                                  \
    __builtin_amdgcn_sched_barrier(0);                                 \
    __builtin_amdgcn_s_setprio(1);                                     \
    _Pragma("unroll") for (int m = 0; m < 4; ++m)                      \
        _Pragma("unroll") for (int n = 0; n < 4; ++n)                  \
            acc[m][n] = mfma16(CA[m], CB[n], acc[m][n]);               \
    __builtin_amdgcn_s_setprio(0);                                     \
    bR = bR + 1; if (bR >= 3) bR -= 3;                                 \
  }

  int nk = K >> 5;  // >= 16 and even at all call sites
  STAGE(0, 0);
  STAGE(1, 32);
  STAGE(2, 64);
  asm volatile("s_waitcnt vmcnt(8)" ::: "memory");  // certify tile 0
  __builtin_amdgcn_s_barrier();
  asm volatile("" ::: "memory");
  __builtin_amdgcn_sched_barrier(0);
  short8 a0[4], b0[4], a1[4], b1[4];
  READS(0, a0, b0);
  int bR = 1;  // buffer of tile kt+1 at kt=0
  for (int kt = 0; kt < nk; kt += 2) {
    STEP(kt, a0, b0, a1, b1);
    STEP(kt + 1, a1, b1, a0, b0);
  }
#undef STEP
#undef READS
#undef STAGE

#pragma unroll
  for (int m = 0; m < 4; ++m) {
    int grow = mbase + wr * 64 + m * 16 + lg * 4;
    float rl[4];
    if (MODE == 3) {
#pragma unroll
      for (int r = 0; r < 4; ++r)
        rl[r] = 1.0f / lsum[lsrow0 + grow + r];
    }
#pragma unroll
    for (int n = 0; n < 4; ++n) {
      int gcol = nbase + wc * 64 + n * 16 + lr;
      if (MODE == 0) {
        // packed 3-way output: col 0..511 -> q, 512..1023 -> k, 1024.. -> v
        float bnc = bias[gcol];
        int which = gcol >> 9;
        int gcolP = gcol & 511;
        u16* op = (u16*)outp + (size_t)which * NROWS * CDIM;
#pragma unroll
        for (int r = 0; r < 4; ++r)
          op[(size_t)(grow + r) * CDIM + gcolP] = f2bf(acc[m][n][r] + bnc);
      } else if (MODE == 1) {
        float bnc = bias[gcol];
#pragma unroll
        for (int r = 0; r < 4; ++r) {
          size_t idx = (size_t)(grow + r) * ldo + gcol;
          ((float*)outp)[idx] = acc[m][n][r] + bnc + res[idx];
        }
      } else if (MODE == 2) {
        u16* op = (u16*)outp + ooff;
#pragma unroll
        for (int r = 0; r < 4; ++r)
          op[(size_t)(grow + r) * ldo + gcol] = f2bf(acc[m][n][r]);
      } else {
        u16* op = (u16*)outp + ooff;
#pragma unroll
        for (int r = 0; r < 4; ++r)
          op[(size_t)(grow + r) * ldo + gcol] = f2bf(acc[m][n][r] * rl[r]);
      }
    }
  }
}

// ---- softmax over rows of 4096 bf16, in-place, one wave per row ----
__global__ __launch_bounds__(256) void softmax_kernel(u16* __restrict__ S,
                                                      float* __restrict__ lsum) {
  int row = blockIdx.x * 4 + (threadIdx.x >> 6);
  int lane = threadIdx.x & 63;
  u16* Sr = S + (size_t)row * NTOK;
  short8 d[8];
#pragma unroll
  for (int i = 0; i < 8; ++i)
    d[i] = *(const short8*)(Sr + i * 512 + lane * 8);
  float mx = -1e30f;
#pragma unroll
  for (int i = 0; i < 8; ++i)
#pragma unroll
    for (int j = 0; j < 8; ++j) mx = fmaxf(mx, bf2f((u16)d[i][j]));
#pragma unroll
  for (int j = 0; j < 6; ++j) mx = fmaxf(mx, __shfl_xor(mx, 1 << j));
  float sum = 0.f;
#pragma unroll
  for (int i = 0; i < 8; ++i) {
    short8 o;
#pragma unroll
    for (int j = 0; j < 8; ++j) {
      float p = __expf(bf2f((u16)d[i][j]) - mx);
      sum += p;
      o[j] = (short)f2bf(p);
    }
    *(short8*)(Sr + i * 512 + lane * 8) = o;
  }
#pragma unroll
  for (int j = 0; j < 6; ++j) sum += __shfl_xor(sum, 1 << j);
  if (lane == 0) lsum[row] = sum;
}

// ---- sum two bf16 partial buffers -> bf16 ----
__global__ __launch_bounds__(256) void addp_kernel(const u16* __restrict__ p0,
                                                   const u16* __restrict__ p1,
                                                   u16* __restrict__ ob) {
  size_t i = ((size_t)blockIdx.x * 256 + threadIdx.x) * 8;
  short8 a = *(const short8*)(p0 + i);
  short8 b = *(const short8*)(p1 + i);
  short8 o;
#pragma unroll
  for (int j = 0; j < 8; ++j)
    o[j] = (short)f2bf(bf2f((u16)a[j]) + bf2f((u16)b[j]));
  *(short8*)(ob + i) = o;
}

extern "C" void kernel_launch(void* const* d_in, const int* in_sizes, int n_in,
                              void* d_out, int out_size, void* d_ws, size_t ws_size,
                              hipStream_t stream) {
  (void)in_sizes; (void)n_in; (void)out_size;
  const float* x    = (const float*)d_in[0];
  const float* ln_g = (const float*)d_in[1];
  const float* ln_b = (const float*)d_in[2];
  const float* Wq   = (const float*)d_in[3];
  const float* bq   = (const float*)d_in[4];
  const float* Wk   = (const float*)d_in[5];
  const float* bk   = (const float*)d_in[6];
  const float* Wv   = (const float*)d_in[7];
  const float* bv   = (const float*)d_in[8];
  const float* Wp   = (const float*)d_in[9];
  const float* bp   = (const float*)d_in[10];

  const size_t MB = 1024ull * 1024ull;
  const size_t KB = 1024ull;
  char* ws = (char*)d_ws;
  u16* wt     = (u16*)(ws);                       // 2 MB [Q|K|V|P] W^T bf16
  float* bqkv = (float*)(ws + 2 * MB);            // 6 KB concat scaled bias
  float* ls   = (float*)(ws + 2 * MB + 64 * KB);  // 64 KB row sums
  u16* hn     = (u16*)(ws + 4 * MB);              // 16 MB (dead after proj)
  u16* qb     = (u16*)(ws + 20 * MB);             // 16 MB packed Q (p0 later)
  u16* kb2    = (u16*)(ws + 36 * MB);             // 16 MB packed K (p1 later)
  u16* vb     = (u16*)(ws + 52 * MB);             // 16 MB packed V
  u16* vt     = (u16*)(ws + 68 * MB);             // 16 MB V^T
  bool full = ws_size >= 212 * MB;
  u16* S    = (u16*)(ws + 84 * MB);   // 128 MB (full) / 32 MB (fallback)
  u16* ob   = hn;                     // hn dead after projection
  u16* p0nf = (u16*)(ws + 116 * MB);  // fallback partials
  u16* p1nf = (u16*)(ws + 124 * MB);

  const float* nullf = nullptr;

  hipLaunchKernelGGL(wconv_kernel, dim3(8, 8, 4), dim3(256), 0, stream,
                     Wq, Wk, Wv, Wp, bq, bk, bv, wt, bqkv);
  hipLaunchKernelGGL(ln_kernel, dim3(NROWS / 4), dim3(256), 0, stream,
                     x, ln_g, ln_b, hn);
  // fused QKV projection -> packed q/k/v [16384,512] each
  hipLaunchKernelGGL((g128_kernel<0, 0>), dim3(12, 128, 1), dim3(256), 0,
                     stream, hn, CDIM, (size_t)0, wt, CDIM, (size_t)0,
                     bqkv, nullf, nullf, 0,
                     (void*)qb, CDIM, (size_t)0, (size_t)0, CDIM);
  // packed V -> vt [B, C, N]
  hipLaunchKernelGGL(vtrans_kernel, dim3(64, 8, 4), dim3(256), 0, stream,
                     vb, CDIM, vt);

  if (full) {
    // S = Q K^T : M=N=4096, K=512, z=4 batches (packed lda=512)
    hipLaunchKernelGGL((g128_kernel<2, 0>), dim3(32, 32, 4), dim3(256), 0,
                       stream, qb, CDIM, (size_t)NTOK * CDIM,
                       kb2, CDIM, (size_t)NTOK * CDIM,
                       nullf, nullf, nullf, 0,
                       (void*)S, NTOK, (size_t)NTOK * NTOK, (size_t)0, CDIM);
    hipLaunchKernelGGL(softmax_kernel, dim3(4 * NTOK / 4), dim3(256), 0, stream,
                       S, ls);
    // O = P V, split-K=2: z = batch*2 + kq; partials into qb (p0) / kb2 (p1)
    hipLaunchKernelGGL((g128_kernel<3, 1>), dim3(4, 32, 8), dim3(256), 0,
                       stream, S, NTOK, (size_t)NTOK * NTOK,
                       vt, NTOK, (size_t)CDIM * NTOK,
                       nullf, nullf, ls, NTOK,
                       (void*)qb, CDIM, (size_t)NTOK * CDIM,
                       (size_t)NROWS * CDIM, NTOK / 2);
    hipLaunchKernelGGL(addp_kernel, dim3(NROWS * CDIM / 2048), dim3(256), 0,
                       stream, qb, kb2, ob);
  } else {
    for (int p = 0; p < 4; ++p) {
      const u16* qp  = qb + (size_t)p * NTOK * CDIM;
      const u16* kp  = kb2 + (size_t)p * NTOK * CDIM;
      const u16* vtp = vt + (size_t)p * CDIM * NTOK;
      u16* obp = ob + (size_t)p * NTOK * CDIM;
      float* lp = ls + (size_t)p * NTOK;
      hipLaunchKernelGGL((g128_kernel<2, 0>), dim3(32, 32, 1), dim3(256), 0,
                         stream, qp, CDIM, (size_t)0, kp, CDIM, (size_t)0,
                         nullf, nullf, nullf, 0,
                         (void*)S, NTOK, (size_t)0, (size_t)0, CDIM);
      hipLaunchKernelGGL(softmax_kernel, dim3(NTOK / 4), dim3(256), 0, stream,
                         S, lp);
      hipLaunchKernelGGL((g128_kernel<3, 1>), dim3(4, 32, 2), dim3(256), 0,
                         stream, S, NTOK, (size_t)0, vtp, NTOK, (size_t)0,
                         nullf, nullf, lp, 0,
                         (void*)p0nf, CDIM, (size_t)0, (size_t)NTOK * CDIM,
                         NTOK / 2);
      hipLaunchKernelGGL(addp_kernel, dim3(NTOK * CDIM / 2048), dim3(256), 0,
                         stream, p0nf, p1nf, obp);
    }
  }
  // final: out = O Wp + bp + x  (f32)
  hipLaunchKernelGGL((g128_kernel<1, 0>), dim3(4, 128, 1), dim3(256), 0,
                     stream, ob, CDIM, (size_t)0,
                     wt + 3 * (size_t)CDIM * CDIM, CDIM, (size_t)0,
                     bp, x, nullf, 0,
                     d_out, CDIM, (size_t)0, (size_t)0, CDIM);
}

// Round 10
// 292.289 us; speedup vs baseline: 1.2910x; 1.0819x over previous
//
#include <hip/hip_runtime.h>
#include <cstdint>
#include <cmath>

typedef unsigned short u16;
typedef __attribute__((ext_vector_type(8))) short short8;
typedef __attribute__((ext_vector_type(4))) float f32x4;

#define BB 4
#define NTOK 4096
#define CDIM 512
#define NROWS (BB * NTOK)
#define QSCALE 0.0441941738241592f  // 1/sqrt(512)

__device__ __forceinline__ u16 f2bf(float f) {
  union { float f; uint32_t u; } v; v.f = f;
  return (u16)((v.u + 0x7fffu + ((v.u >> 16) & 1u)) >> 16);
}

__device__ __forceinline__ float bf2f(u16 u) {
  union { uint32_t u; float f; } v; v.u = (uint32_t)u << 16;
  return v.f;
}

__device__ __forceinline__ f32x4 mfma16(short8 a, short8 b, f32x4 c) {
  return __builtin_amdgcn_mfma_f32_16x16x32_bf16(a, b, c, 0, 0, 0);
}

__device__ __forceinline__ void gload16(const u16* g, u16* l) {
  __builtin_amdgcn_global_load_lds(
      (const __attribute__((address_space(1))) void*)g,
      (__attribute__((address_space(3))) void*)l, 16, 0, 0);
}

// ---------------- LayerNorm (one wave per row of 512) ----------------
__global__ __launch_bounds__(256) void ln_kernel(const float* __restrict__ x,
                                                 const float* __restrict__ gam,
                                                 const float* __restrict__ bet,
                                                 u16* __restrict__ hn) {
  int row = blockIdx.x * 4 + (threadIdx.x >> 6);
  int lane = threadIdx.x & 63;
  const float4* xr = (const float4*)(x + (size_t)row * CDIM);
  float4 a0 = xr[lane];
  float4 a1 = xr[lane + 64];
  float s = a0.x + a0.y + a0.z + a0.w + a1.x + a1.y + a1.z + a1.w;
  float ss = a0.x * a0.x + a0.y * a0.y + a0.z * a0.z + a0.w * a0.w +
             a1.x * a1.x + a1.y * a1.y + a1.z * a1.z + a1.w * a1.w;
#pragma unroll
  for (int j = 0; j < 6; ++j) {
    s += __shfl_xor(s, 1 << j);
    ss += __shfl_xor(ss, 1 << j);
  }
  float mu = s * (1.0f / CDIM);
  float var = ss * (1.0f / CDIM) - mu * mu;
  float rs = rsqrtf(var + 1e-3f);
  const float4* g4 = (const float4*)gam;
  const float4* b4 = (const float4*)bet;
  float4 g0 = g4[lane], g1 = g4[lane + 64];
  float4 c0 = b4[lane], c1 = b4[lane + 64];
  u16* out = hn + (size_t)row * CDIM;
  ushort4 o0, o1;
  o0.x = f2bf((a0.x - mu) * rs * g0.x + c0.x);
  o0.y = f2bf((a0.y - mu) * rs * g0.y + c0.y);
  o0.z = f2bf((a0.z - mu) * rs * g0.z + c0.z);
  o0.w = f2bf((a0.w - mu) * rs * g0.w + c0.w);
  o1.x = f2bf((a1.x - mu) * rs * g1.x + c1.x);
  o1.y = f2bf((a1.y - mu) * rs * g1.y + c1.y);
  o1.z = f2bf((a1.z - mu) * rs * g1.z + c1.z);
  o1.w = f2bf((a1.w - mu) * rs * g1.w + c1.w);
  *(ushort4*)(out + lane * 4) = o0;
  *(ushort4*)(out + 256 + lane * 4) = o1;
}

// -- weights fp32 [K,N] -> bf16 W^T rows [Q|K|V|P] [2048,512]; Q pre-scaled.
__global__ __launch_bounds__(256) void wconv_kernel(
    const float* __restrict__ w0, const float* __restrict__ w1,
    const float* __restrict__ w2, const float* __restrict__ w3,
    const float* __restrict__ bq, const float* __restrict__ bk,
    const float* __restrict__ bv,
    u16* __restrict__ wt, float* __restrict__ bqkv) {
  __shared__ __align__(16) u16 tile[64][65];
  int which = blockIdx.z;
  const float* W = (which == 0) ? w0 : (which == 1) ? w1 : (which == 2) ? w2 : w3;
  float wscale = (which == 0) ? QSCALE : 1.0f;
  u16* WT = wt + (size_t)which * CDIM * CDIM;
  int kb = blockIdx.x * 64, nb = blockIdx.y * 64;
  int t = threadIdx.x;
  if (kb == 0 && which < 3 && t < 64) {
    const float* bs = (which == 0) ? bq : (which == 1) ? bk : bv;
    bqkv[which * CDIM + nb + t] = bs[nb + t] * wscale;
  }
#pragma unroll
  for (int i = 0; i < 16; ++i) {
    int idx = t + i * 256;
    int r = idx >> 6, c = idx & 63;
    tile[r][c] = f2bf(W[(size_t)(kb + r) * CDIM + nb + c] * wscale);
  }
  __syncthreads();
#pragma unroll
  for (int i = 0; i < 16; ++i) {
    int idx = t + i * 256;
    int r = idx >> 6, c = idx & 63;
    WT[(size_t)(nb + r) * CDIM + kb + c] = tile[c][r];
  }
}

// ------- bf16 src [BN, ld] (col window 64) -> vt [B, C, N] transpose -------
__global__ __launch_bounds__(256) void vtrans_kernel(const u16* __restrict__ v,
                                                     int ld,
                                                     u16* __restrict__ vt) {
  __shared__ __align__(16) u16 tile[64][65];
  int nb = blockIdx.x * 64;
  int cb = blockIdx.y * 64;
  int b = blockIdx.z;
  int t = threadIdx.x;
  const u16* src = v + ((size_t)b * NTOK + nb) * ld + cb;
#pragma unroll
  for (int i = 0; i < 16; ++i) {
    int idx = t + i * 256;
    int r = idx >> 6, c = idx & 63;
    tile[r][c] = src[(size_t)r * ld + c];
  }
  __syncthreads();
  u16* dst = vt + ((size_t)b * CDIM + cb) * NTOK + nb;
#pragma unroll
  for (int i = 0; i < 16; ++i) {
    int idx = t + i * 256;
    int r = idx >> 6, c = idx & 63;
    dst[(size_t)r * NTOK + c] = tile[c][r];
  }
}

// ====== 256x256 GEMM, 8 waves (2M x 4N), BK=64, 8-phase schedule ======
// Spill-safe retry of the m201-style schedule (R7's failure was VGPR spill,
// diagnosed via +66MB WRITE_SIZE scratch traffic; schedule itself refcheck'd).
// Quadrant order per tile: P1(0,0) P2(0,1) P3(1,1) P4(1,0) -- only B0 (16
// VGPR) is held 4 phases; A-sets live <=2 phases. Peak frag regs ~64.
// Stages: exactly one region per phase, write-after-read gap >= 3 barriers:
//   d1-refill(T2j+1): prevP8.Bh0, P1.Bh1, P2.Ah0, P3.Ah1
//   d0-refill(T2j+2): P4.Bh0, P5.Bh1, P6.Ah0, P7.Ah1
// VM2 at P4 certifies d1's 4 regions; VM2 at P8 certifies d0's 4 regions;
// VM0 in last iteration only.
// Swizzle (verified, 0 conflicts in R7): phys 16B-slot p of row r holds
// logical slot p^(r&7); linear gload dest + pre-swizzled global source.
// MODE 0: bf16 acc+bias | MODE 2: bf16 acc | MODE 3: bf16 acc/lsum[row]
template <int MODE, int LOGSPLIT>
__global__ __launch_bounds__(512) void gemm256_kernel(
    const u16* __restrict__ A, int lda, size_t az,
    const u16* __restrict__ Bt, int ldb, size_t bz,
    const float* __restrict__ bias,
    const float* __restrict__ lsum, int lz,
    u16* __restrict__ outp, int ldo, size_t oz, size_t koz,
    int K) {
  // regions [dbuf*4 + {Ah0,Ah1,Bh0,Bh1}] of 8192 u16 (128 rows x 64)
  __shared__ __align__(16) u16 lds[8][8192];
  int t = threadIdx.x;
  int w = t >> 6, lane = t & 63;
  int lr = lane & 15, lg = lane >> 4;
  int wr = w >> 2, wc = w & 3;
  // --- XCD-chunked bijective swizzle (nwg % 8 == 0 at all call sites) ---
  int gx = gridDim.x, gy = gridDim.y;
  int nwg = gx * gy * (int)gridDim.z;
  int nlin = blockIdx.x + gx * (blockIdx.y + gy * blockIdx.z);
  int cpx = nwg >> 3;
  int swz = (nlin & 7) * cpx + (nlin >> 3);
  int bx = swz % gx;
  int rem = swz / gx;
  int by = rem % gy;
  int bz2 = rem / gy;
  int batch = bz2 >> LOGSPLIT;
  int kq = bz2 & ((1 << LOGSPLIT) - 1);
  size_t aoff = az * (size_t)batch + (size_t)kq * K;
  size_t boff = bz * (size_t)batch + (size_t)kq * K;
  size_t ooff = oz * (size_t)batch + koz * (size_t)kq;
  int lsrow0 = lz * batch;
  int mbase = by * 256, nbase = bx * 256;
  const f32x4 fz = {0.f, 0.f, 0.f, 0.f};
  f32x4 acc[8][4];
#pragma unroll
  for (int m = 0; m < 8; ++m)
#pragma unroll
    for (int n2 = 0; n2 < 4; ++n2) acc[m][n2] = fz;

  // staging: thread t -> row t>>3 (64 rows/gload), phys slot t&7; source
  // col-slot pre-swizzled by row&7 (rule #21; linear LDS dest).
  int srow = t >> 3;
  int scol = ((t & 7) ^ (srow & 7)) * 8;
  const u16* ga = A + aoff + (size_t)(mbase + srow) * lda + scol;
  const u16* gb = Bt + boff + (size_t)(nbase + srow) * ldb + scol;
  // read-side phys slot offsets (u16 elems): ks=0 and ks=1
  int pse0 = (lg ^ (lr & 7)) * 8;
  int pse1 = pse0 ^ 32;

#define STG_A(h, tile, d)                                              \
  {                                                                    \
    const u16* s_ = ga + (size_t)((h)*128) * lda + (tile)*64;          \
    u16* d_ = &lds[(d)*4 + (h)][0] + w * 512;                          \
    gload16(s_, d_);                                                   \
    gload16(s_ + (size_t)64 * lda, d_ + 4096);                        \
  }
#define STG_B(h, tile, d)                                              \
  {                                                                    \
    const u16* s_ = gb + (size_t)((h)*128) * ldb + (tile)*64;          \
    u16* d_ = &lds[(d)*4 + 2 + (h)][0] + w * 512;                      \
    gload16(s_, d_);                                                   \
    gload16(s_ + (size_t)64 * ldb, d_ + 4096);                        \
  }

#define RD_A(dst, d, mh)                                               \
  {                                                                    \
    const u16* p_ = &lds[(d)*4 + wr][0] + (((mh)*64 + lr) << 6);       \
    _Pragma("unroll") for (int m = 0; m < 4; ++m) {                    \
      dst[m * 2 + 0] = *(const short8*)(p_ + (m << 10) + pse0);        \
      dst[m * 2 + 1] = *(const short8*)(p_ + (m << 10) + pse1);        \
    }                                                                  \
  }
#define RD_B(dst, d, nh)                                               \
  {                                                                    \
    const u16* p_ = &lds[(d)*4 + 2 + (wc >> 1)][0] +                   \
                    (((wc & 1) * 64 + (nh)*32 + lr) << 6);             \
    _Pragma("unroll") for (int n2 = 0; n2 < 2; ++n2) {                 \
      dst[n2 * 2 + 0] = *(const short8*)(p_ + (n2 << 10) + pse0);      \
      dst[n2 * 2 + 1] = *(const short8*)(p_ + (n2 << 10) + pse1);      \
    }                                                                  \
  }

#define PHEND                                                          \
  asm volatile("" ::: "memory");                                       \
  __builtin_amdgcn_sched_barrier(0);                                   \
  __builtin_amdgcn_s_barrier();                                        \
  asm volatile("s_waitcnt lgkmcnt(0)" ::: "memory");                   \
  __builtin_amdgcn_sched_barrier(0);

#define VM2 asm volatile("s_waitcnt vmcnt(2)" ::: "memory");
#define VM0 asm volatile("s_waitcnt vmcnt(0)" ::: "memory");

#define MM(X, Y, mq, nq)                                               \
  __builtin_amdgcn_s_setprio(1);                                       \
  _Pragma("unroll") for (int m = 0; m < 4; ++m)                        \
      _Pragma("unroll") for (int n2 = 0; n2 < 2; ++n2)                 \
          _Pragma("unroll") for (int ks = 0; ks < 2; ++ks)             \
              acc[(mq)*4 + m][(nq)*2 + n2] =                           \
                  mfma16(X[m * 2 + ks], Y[n2 * 2 + ks],                \
                         acc[(mq)*4 + m][(nq)*2 + n2]);                \
  __builtin_amdgcn_s_setprio(0);

  short8 Af[8], Ag[8], Bf[4], Bg[4];
  int niter = K >> 7;  // K/128, >= 4 at all call sites

  // prologue: T0 full -> d0; T1.Bh0 -> d1 ("P8 of iter -1")
  STG_A(0, 0, 0); STG_A(1, 0, 0); STG_B(0, 0, 0); STG_B(1, 0, 0);
  STG_B(0, 1, 1);
  VM2;
  __builtin_amdgcn_s_barrier();
  asm volatile("" ::: "memory");
  __builtin_amdgcn_sched_barrier(0);

  for (int j = 0; j < niter; ++j) {
    int T1i = 2 * j + 1, T2i = 2 * j + 2, T3i = 2 * j + 3;
    bool more = (j + 1 < niter);
    // P1: rd A0,B0 (d0); stage T1.Bh1 -> d1
    RD_A(Af, 0, 0); RD_B(Bf, 0, 0);
    STG_B(1, T1i, 1);
    PHEND; MM(Af, Bf, 0, 0);
    // P2: rd B1 (d0); stage T1.Ah0 -> d1
    RD_B(Bg, 0, 1);
    STG_A(0, T1i, 1);
    PHEND; MM(Af, Bg, 0, 1);
    // P3: rd A1 (d0); stage T1.Ah1 -> d1
    RD_A(Ag, 0, 1);
    STG_A(1, T1i, 1);
    PHEND; MM(Ag, Bg, 1, 1);
    // P4: stage T2.Bh0 -> d0; VM2 certifies T1's 4 regions
    if (more) { STG_B(0, T2i, 0); VM2; } else { VM0; }
    PHEND; MM(Ag, Bf, 1, 0);
    // P5: rd A0,B0 (d1); stage T2.Bh1 -> d0
    RD_A(Af, 1, 0); RD_B(Bf, 1, 0);
    if (more) STG_B(1, T2i, 0);
    PHEND; MM(Af, Bf, 0, 0);
    // P6: rd B1 (d1); stage T2.Ah0 -> d0
    RD_B(Bg, 1, 1);
    if (more) STG_A(0, T2i, 0);
    PHEND; MM(Af, Bg, 0, 1);
    // P7: rd A1 (d1); stage T2.Ah1 -> d0
    RD_A(Ag, 1, 1);
    if (more) STG_A(1, T2i, 0);
    PHEND; MM(Ag, Bg, 1, 1);
    // P8: stage T3.Bh0 -> d1; VM2 certifies T2's 4 regions
    if (more) { STG_B(0, T3i, 1); VM2; } else { VM0; }
    PHEND; MM(Ag, Bf, 1, 0);
  }
#undef MM
#undef VM2
#undef VM0
#undef PHEND
#undef RD_A
#undef RD_B
#undef STG_A
#undef STG_B

  u16* op = outp + ooff;
#pragma unroll
  for (int m = 0; m < 8; ++m) {
    int grow = mbase + wr * 128 + m * 16 + lg * 4;
    float rl[4];
    if (MODE == 3) {
#pragma unroll
      for (int r = 0; r < 4; ++r)
        rl[r] = 1.0f / lsum[lsrow0 + grow + r];
    }
#pragma unroll
    for (int n2 = 0; n2 < 4; ++n2) {
      int gcol = nbase + wc * 64 + n2 * 16 + lr;
      float bnc = (MODE == 0) ? bias[gcol] : 0.f;
#pragma unroll
      for (int r = 0; r < 4; ++r) {
        size_t idx = (size_t)(grow + r) * ldo + gcol;
        float val = acc[m][n2][r];
        if (MODE == 0) {
          op[idx] = f2bf(val + bnc);
        } else if (MODE == 2) {
          op[idx] = f2bf(val);
        } else {
          op[idx] = f2bf(val * rl[r]);
        }
      }
    }
  }
}

// ====== 128x128 GEMM (final projection): f32 store acc+bias+res ======
__global__ __launch_bounds__(256) void gemm_fin_kernel(
    const u16* __restrict__ A, int lda,
    const u16* __restrict__ Bt, int ldb,
    const float* __restrict__ bias, const float* __restrict__ res,
    float* __restrict__ outp, int ldo, int K) {
  __shared__ __align__(16) u16 Als[2][128 * 32];
  __shared__ __align__(16) u16 Bls[2][128 * 32];
  int t = threadIdx.x;
  int w = t >> 6, lane = t & 63;
  int lr = lane & 15, lg = lane >> 4;
  int wr = w >> 1, wc = w & 1;
  int mbase = blockIdx.y * 128, nbase = blockIdx.x * 128;
  const f32x4 fz = {0.f, 0.f, 0.f, 0.f};
  f32x4 acc[4][4];
#pragma unroll
  for (int m = 0; m < 4; ++m)
#pragma unroll
    for (int n = 0; n < 4; ++n) acc[m][n] = fz;

  int scol = (((t & 3) ^ ((t >> 2) & 3) ^ ((t >> 4) & 1)) * 8);
  const u16* ga0 = A + (size_t)(mbase + (t >> 2)) * lda + scol;
  const u16* gb0 = Bt + (size_t)(nbase + (t >> 2)) * ldb + scol;
  int rsA = (lg ^ (lr & 3) ^ ((lr >> 2) & 1)) * 8;

#define STAGE(buf, ko)                                                 \
  {                                                                    \
    gload16(ga0 + (ko), &Als[buf][w * 512]);                           \
    gload16(ga0 + (size_t)64 * lda + (ko), &Als[buf][w * 512 + 2048]); \
    gload16(gb0 + (ko), &Bls[buf][w * 512]);                           \
    gload16(gb0 + (size_t)64 * ldb + (ko), &Bls[buf][w * 512 + 2048]); \
  }

  int nk = K >> 5;
  STAGE(0, 0);
  STAGE(1, 32);
  int cur = 0;
  for (int kt = 0; kt < nk; ++kt) {
    if (kt + 1 < nk) {
      asm volatile("s_waitcnt vmcnt(4)" ::: "memory");
    } else {
      asm volatile("s_waitcnt vmcnt(0)" ::: "memory");
    }
    __builtin_amdgcn_s_barrier();
    asm volatile("" ::: "memory");
    __builtin_amdgcn_sched_barrier(0);
    short8 af[4], bfr[4];
#pragma unroll
    for (int m = 0; m < 4; ++m)
      af[m] = *(const short8*)(&Als[cur][(wr * 64 + m * 16 + lr) * 32 + rsA]);
#pragma unroll
    for (int n = 0; n < 4; ++n)
      bfr[n] = *(const short8*)(&Bls[cur][(wc * 64 + n * 16 + lr) * 32 + rsA]);
#pragma unroll
    for (int m = 0; m < 4; ++m)
#pragma unroll
      for (int n = 0; n < 4; ++n)
        acc[m][n] = mfma16(af[m], bfr[n], acc[m][n]);
    asm volatile("s_waitcnt lgkmcnt(0)" ::: "memory");
    __builtin_amdgcn_s_barrier();
    asm volatile("" ::: "memory");
    if (kt + 2 < nk) STAGE(cur, (kt + 2) * 32);
    cur ^= 1;
  }
#undef STAGE

#pragma unroll
  for (int m = 0; m < 4; ++m) {
    int grow = mbase + wr * 64 + m * 16 + lg * 4;
#pragma unroll
    for (int n = 0; n < 4; ++n) {
      int gcol = nbase + wc * 64 + n * 16 + lr;
      float bnc = bias[gcol];
#pragma unroll
      for (int r = 0; r < 4; ++r) {
        size_t idx = (size_t)(grow + r) * ldo + gcol;
        outp[idx] = acc[m][n][r] + bnc + res[idx];
      }
    }
  }
}

// ---- softmax over rows of 4096 bf16, in-place, one wave per row ----
__global__ __launch_bounds__(256) void softmax_kernel(u16* __restrict__ S,
                                                      float* __restrict__ lsum) {
  int row = blockIdx.x * 4 + (threadIdx.x >> 6);
  int lane = threadIdx.x & 63;
  u16* Sr = S + (size_t)row * NTOK;
  short8 d[8];
#pragma unroll
  for (int i = 0; i < 8; ++i)
    d[i] = *(const short8*)(Sr + i * 512 + lane * 8);
  float mx = -1e30f;
#pragma unroll
  for (int i = 0; i < 8; ++i)
#pragma unroll
    for (int j = 0; j < 8; ++j) mx = fmaxf(mx, bf2f((u16)d[i][j]));
#pragma unroll
  for (int j = 0; j < 6; ++j) mx = fmaxf(mx, __shfl_xor(mx, 1 << j));
  float sum = 0.f;
#pragma unroll
  for (int i = 0; i < 8; ++i) {
    short8 o;
#pragma unroll
    for (int j = 0; j < 8; ++j) {
      float p = __expf(bf2f((u16)d[i][j]) - mx);
      sum += p;
      o[j] = (short)f2bf(p);
    }
    *(short8*)(Sr + i * 512 + lane * 8) = o;
  }
#pragma unroll
  for (int j = 0; j < 6; ++j) sum += __shfl_xor(sum, 1 << j);
  if (lane == 0) lsum[row] = sum;
}

// ---- sum four bf16 partial slices (stride ss) -> bf16 ----
__global__ __launch_bounds__(256) void addp4_kernel(const u16* __restrict__ p,
                                                    size_t ss,
                                                    u16* __restrict__ ob) {
  size_t i = ((size_t)blockIdx.x * 256 + threadIdx.x) * 8;
  short8 a0 = *(const short8*)(p + i);
  short8 a1 = *(const short8*)(p + ss + i);
  short8 a2 = *(const short8*)(p + 2 * ss + i);
  short8 a3 = *(const short8*)(p + 3 * ss + i);
  short8 o;
#pragma unroll
  for (int j = 0; j < 8; ++j)
    o[j] = (short)f2bf(bf2f((u16)a0[j]) + bf2f((u16)a1[j]) +
                       bf2f((u16)a2[j]) + bf2f((u16)a3[j]));
  *(short8*)(ob + i) = o;
}

extern "C" void kernel_launch(void* const* d_in, const int* in_sizes, int n_in,
                              void* d_out, int out_size, void* d_ws, size_t ws_size,
                              hipStream_t stream) {
  (void)in_sizes; (void)n_in; (void)out_size;
  const float* x    = (const float*)d_in[0];
  const float* ln_g = (const float*)d_in[1];
  const float* ln_b = (const float*)d_in[2];
  const float* Wq   = (const float*)d_in[3];
  const float* bq   = (const float*)d_in[4];
  const float* Wk   = (const float*)d_in[5];
  const float* bk   = (const float*)d_in[6];
  const float* Wv   = (const float*)d_in[7];
  const float* bv   = (const float*)d_in[8];
  const float* Wp   = (const float*)d_in[9];
  const float* bp   = (const float*)d_in[10];

  const size_t MB = 1024ull * 1024ull;
  const size_t KB = 1024ull;
  char* ws = (char*)d_ws;
  u16* wt     = (u16*)(ws);                       // 2 MB [Q|K|V|P] W^T bf16
  float* bqkv = (float*)(ws + 2 * MB);            // 6 KB concat scaled bias
  float* ls   = (float*)(ws + 2 * MB + 64 * KB);  // 64 KB row sums
  u16* hn     = (u16*)(ws + 4 * MB);              // 16 MB (dead after proj)
  u16* qkv    = (u16*)(ws + 20 * MB);             // 48 MB [16384,1536]
  u16* vt     = (u16*)(ws + 68 * MB);             // 16 MB
  bool full = ws_size >= 212 * MB;
  u16* S    = (u16*)(ws + 84 * MB);   // 128 MB (full) / 32 MB (fallback)
  // PV split-K=4 partials: 4 x 16 MB = 64 MB over dead hn+qkv (full path)
  u16* part = (u16*)(ws + 4 * MB);
  u16* ob   = full ? vt : (u16*)(ws + 116 * MB);  // vt dead after PV (full)

  const float* nullf = nullptr;

  hipLaunchKernelGGL(wconv_kernel, dim3(8, 8, 4), dim3(256), 0, stream,
                     Wq, Wk, Wv, Wp, bq, bk, bv, wt, bqkv);
  hipLaunchKernelGGL(ln_kernel, dim3(NROWS / 4), dim3(256), 0, stream,
                     x, ln_g, ln_b, hn);
  // fused QKV projection: [16384,512] x [1536,512]^T -> qkv [16384,1536]
  hipLaunchKernelGGL((gemm256_kernel<0, 0>), dim3(6, 64, 1), dim3(512), 0,
                     stream, hn, CDIM, (size_t)0, wt, CDIM, (size_t)0,
                     bqkv, nullf, 0, qkv, 3 * CDIM, (size_t)0, (size_t)0, CDIM);
  // V columns of qkv -> vt [B, C, N]
  hipLaunchKernelGGL(vtrans_kernel, dim3(64, 8, 4), dim3(256), 0, stream,
                     qkv + 2 * CDIM, 3 * CDIM, vt);

  if (full) {
    // S = Q K^T : M=N=4096, K=512, z=4 batches
    hipLaunchKernelGGL((gemm256_kernel<2, 0>), dim3(16, 16, 4), dim3(512), 0,
                       stream, qkv, 3 * CDIM, (size_t)NTOK * 3 * CDIM,
                       qkv + CDIM, 3 * CDIM, (size_t)NTOK * 3 * CDIM,
                       nullf, nullf, 0,
                       S, NTOK, (size_t)NTOK * NTOK, (size_t)0, CDIM);
    hipLaunchKernelGGL(softmax_kernel, dim3(4 * NTOK / 4), dim3(256), 0, stream,
                       S, ls);
    // O = P V, split-K=4: z = batch*4+kq; partials into part[kq][batch]
    hipLaunchKernelGGL((gemm256_kernel<3, 2>), dim3(2, 16, 16), dim3(512), 0,
                       stream, S, NTOK, (size_t)NTOK * NTOK,
                       vt, NTOK, (size_t)CDIM * NTOK,
                       nullf, ls, NTOK,
                       part, CDIM, (size_t)NTOK * CDIM,
                       (size_t)NROWS * CDIM, NTOK / 4);
    hipLaunchKernelGGL(addp4_kernel, dim3(NROWS * CDIM / 2048), dim3(256), 0,
                       stream, part, (size_t)NROWS * CDIM, ob);
  } else {
    for (int p = 0; p < 4; ++p) {
      const u16* qp  = qkv + (size_t)p * NTOK * 3 * CDIM;
      const u16* kp  = qp + CDIM;
      const u16* vtp = vt + (size_t)p * CDIM * NTOK;
      u16* obp = ob + (size_t)p * NTOK * CDIM;
      float* lp = ls + (size_t)p * NTOK;
      hipLaunchKernelGGL((gemm256_kernel<2, 0>), dim3(16, 16, 1), dim3(512), 0,
                         stream, qp, 3 * CDIM, (size_t)0, kp, 3 * CDIM,
                         (size_t)0, nullf, nullf, 0,
                         S, NTOK, (size_t)0, (size_t)0, CDIM);
      hipLaunchKernelGGL(softmax_kernel, dim3(NTOK / 4), dim3(256), 0, stream,
                         S, lp);
      hipLaunchKernelGGL((gemm256_kernel<3, 0>), dim3(2, 16, 1), dim3(512), 0,
                         stream, S, NTOK, (size_t)0, vtp, NTOK, (size_t)0,
                         nullf, lp, 0,
                         obp, CDIM, (size_t)0, (size_t)0, NTOK);
    }
  }
  // final: out = O Wp + bp + x  (f32)
  hipLaunchKernelGGL(gemm_fin_kernel, dim3(4, 128), dim3(256), 0, stream,
                     ob, CDIM, wt + 3 * CDIM * CDIM, CDIM,
                     bp, x, (float*)d_out, CDIM, CDIM);
}